// Round 10
// baseline (405.180 us; speedup 1.0000x reference)
//
#include <hip/hip_runtime.h>
#include <hip/hip_bf16.h>

// Problem constants
#define N_TOK 8192
#define N_EXP 8
#define DIM   2048
#define HID   2048

typedef __attribute__((ext_vector_type(8))) short short8;
typedef __attribute__((ext_vector_type(4))) float f32x4;
typedef __attribute__((ext_vector_type(4))) unsigned short ushort4v;

__device__ inline unsigned short f2bf(float f) {
  unsigned int u = __builtin_bit_cast(unsigned int, f);
  unsigned int r = u + 0x7FFFu + ((u >> 16) & 1u);   // round-to-nearest-even
  return (unsigned short)(r >> 16);
}

// ---------------------------------------------------------------------------
// Kernel 1: stable counting sort by expert id + 256-row band table + queue.
// perm[p] = source row; offs[e..e+1] = bounds; bands[0] = nb,
// bands[1+i] = e | (absRowStart << 8); qcnt[0] = 512 (queue start).
// ---------------------------------------------------------------------------
__global__ __launch_bounds__(256) void sort_experts(const int* __restrict__ idx,
                                                    int* __restrict__ perm,
                                                    int* __restrict__ offs,
                                                    int* __restrict__ bands,
                                                    int* __restrict__ qcnt) {
  __shared__ int cnt[256][8];
  __shared__ int base[8];
  const int t = threadIdx.x;
  int local[8] = {0,0,0,0,0,0,0,0};
  const int r0 = t * 32;
  for (int i = 0; i < 32; ++i) {
    int e = idx[r0 + i] & 7;
    ++local[e];
  }
#pragma unroll
  for (int e = 0; e < 8; ++e) cnt[t][e] = local[e];
  __syncthreads();
  if (t < 8) {
    int s = 0;
    for (int i = 0; i < 256; ++i) { int v = cnt[i][t]; cnt[i][t] = s; s += v; }
    base[t] = s;
  }
  __syncthreads();
  if (t == 0) {
    int s = 0, nb = 0;
    for (int e = 0; e < 8; ++e) {
      int v = base[e];
      offs[e] = s; base[e] = s;
      int nm = (v + 255) >> 8;             // 256-row bands
      for (int mt = 0; mt < nm; ++mt) bands[1 + nb++] = e | ((s + mt * 256) << 8);
      s += v;
    }
    offs[8] = s;
    bands[0] = nb;
    qcnt[0] = 512;                          // queue starts after initial grid
  }
  __syncthreads();
  int pos[8];
#pragma unroll
  for (int e = 0; e < 8; ++e) pos[e] = base[e] + cnt[t][e];
  for (int i = 0; i < 32; ++i) {
    int r = r0 + i;
    int e = idx[r] & 7;
    perm[pos[e]++] = r;
  }
}

// ---------------------------------------------------------------------------
// Kernel 2: W[e][d][h] fp32 -> Wt[e][h][d] bf16 (LDS-tiled transpose).
// (x-gather prep is gone: GEMM reads x directly via perm.)
// ---------------------------------------------------------------------------
__global__ __launch_bounds__(256) void prep_w(const float* __restrict__ W,
                                              unsigned short* __restrict__ Wt) {
  __shared__ unsigned short tile[64][68];
  const int t = threadIdx.x;
  const int b = blockIdx.x;
  const int e  = b >> 10;
  const int d0 = ((b >> 5) & 31) * 64;
  const int h0 = (b & 31) * 64;
  const int cr = t & 15;
  const int rr = t >> 4;
  const float* Wp = W + ((size_t)e * DIM + d0) * HID + h0;
#pragma unroll
  for (int i = 0; i < 4; ++i) {
    int d = rr + i * 16;
    float4 v = *(const float4*)(Wp + (size_t)d * HID + cr * 4);
    ushort4v o;
    o[0] = f2bf(v.x); o[1] = f2bf(v.y); o[2] = f2bf(v.z); o[3] = f2bf(v.w);
    *(ushort4v*)&tile[d][cr * 4] = o;
  }
  __syncthreads();
  unsigned short* op = Wt + ((size_t)e * HID + h0) * DIM + d0;
#pragma unroll
  for (int i = 0; i < 4; ++i) {
    int h = rr + i * 16;
    ushort4v o;
    o[0] = tile[cr * 4 + 0][h];
    o[1] = tile[cr * 4 + 1][h];
    o[2] = tile[cr * 4 + 2][h];
    o[3] = tile[cr * 4 + 3][h];
    *(ushort4v*)(op + (size_t)h * DIM + cr * 4) = o;
  }
}

// ---------------------------------------------------------------------------
// Kernel 3: grouped GEMM, A-DIRECT + B-LDS. 512 blocks x 256 thr (4 waves),
// 2 blocks/CU. Job = 256(M) x 128(N); wave = 64M x 128N (acc 4x8).
// A: per-lane gather from fp32 x via perm, cvt to bf16 in-register (no LDS,
// no staging drain). B: Wt bf16 staged via gload_lds, 16 KB/K-tile, 3 slots,
// depth-2 counted vmcnt(4), ONE barrier per K-tile. Swizzle (verified):
// byte[6:4] ^= row[2:0] on reads, inverse pre-applied to staging source.
// ---------------------------------------------------------------------------
#define NKT 32   // K-tiles of 64
#define SLOT 8192  // ushorts per B slot (16 KB)

#define MM(D,A,B) D = __builtin_amdgcn_mfma_f32_16x16x32_bf16(A, B, D, 0, 0, 0)
#define GLD(SRC, DST) __builtin_amdgcn_global_load_lds( \
    (const __attribute__((address_space(1))) void*)(SRC), \
    (__attribute__((address_space(3))) void*)(DST), 16, 0, 0)
#define BAR() __builtin_amdgcn_s_barrier()

__device__ inline short8 cvt_frag(float4 a, float4 b) {
  short8 o;
  o[0] = (short)f2bf(a.x); o[1] = (short)f2bf(a.y);
  o[2] = (short)f2bf(a.z); o[3] = (short)f2bf(a.w);
  o[4] = (short)f2bf(b.x); o[5] = (short)f2bf(b.y);
  o[6] = (short)f2bf(b.z); o[7] = (short)f2bf(b.w);
  return o;
}

__global__ __launch_bounds__(256, 2) void grouped_gemm(
    const float* __restrict__ x,
    const int* __restrict__ perm,
    const unsigned short* __restrict__ Wt,
    const float* __restrict__ bias,
    const int* __restrict__ offs,
    const int* __restrict__ bands,
    int* __restrict__ qcnt,
    float* __restrict__ out) {
  __shared__ __align__(16) unsigned short sm[3 * SLOT];   // 48 KiB (B only)
  __shared__ int next_j;

  const int t    = threadIdx.x;
  const int lane = t & 63;
  const int w    = t >> 6;     // wave 0..3: C rows w*64..w*64+63
  const int l15  = lane & 15;
  const int l4   = lane >> 4;

  // B fragment read offsets (ushort units; rows of 64 ush = 128 B, swizzled).
  const int cb0  = (l4 * 8) ^ ((l15 & 7) << 3);
  const int cb1  = cb0 ^ 32;
  const int brow = l15 * 64;               // + n*1024 within a slot

  // B staging: 4 chunks of 4 KB; thread t covers row r0 = t>>3 of a 32-row
  // chunk, 16B col t&7; inverse swizzle pre-applied to global k index.
  const int r0  = t >> 3;
  const int keu = ((t & 7) * 8) ^ ((r0 & 7) << 3);
  const int dB  = t * 8;                   // ushort offset within a 4KB chunk

  const int total = bands[0] * 16;

  int j = blockIdx.x;
  while (j < total) {
    const int bd    = bands[1 + (j >> 4)];
    const int e     = bd & 255;
    const int aBase = bd >> 8;             // absolute sorted row of band start
    const int hi    = offs[e + 1];         // expert end (mask bound)
    const int nx    = j & 15;
    const int n0    = nx * 128;

    // Per-lane A source rows (gathered through perm, clamped for safety).
    const float* pA[4];
#pragma unroll
    for (int m = 0; m < 4; ++m) {
      int r = aBase + w * 64 + m * 16 + l15;
      if (r > N_TOK - 1) r = N_TOK - 1;
      pA[m] = x + (size_t)perm[r] * DIM;
    }

    // B staging source base (ushort elements, k=0).
    const unsigned int pb = ((unsigned)e * 2048 + n0 + r0) * 2048u + keu;

#define ST_B(SLOTI, KOFS) do { \
    GLD(Wt + pb + 0u * 65536u + (KOFS), sm + (SLOTI) * SLOT + 0 * 2048 + dB); \
    GLD(Wt + pb + 1u * 65536u + (KOFS), sm + (SLOTI) * SLOT + 1 * 2048 + dB); \
    GLD(Wt + pb + 2u * 65536u + (KOFS), sm + (SLOTI) * SLOT + 2 * 2048 + dB); \
    GLD(Wt + pb + 3u * 65536u + (KOFS), sm + (SLOTI) * SLOT + 3 * 2048 + dB); } while (0)

    f32x4 acc[4][8];
#pragma unroll
    for (int m = 0; m < 4; ++m)
#pragma unroll
      for (int n = 0; n < 8; ++n) acc[m][n] = (f32x4){0.f, 0.f, 0.f, 0.f};

    // Prologue: B tiles 0,1 -> slots 0,1.
    ST_B(0, 0);
    ST_B(1, 64);
    asm volatile("s_waitcnt vmcnt(4)" ::: "memory");   // tile0 landed
    BAR();

    int sl = 0;   // slot of tile T
    int s2 = 2;   // slot of tile T+2

#pragma unroll 1
    for (int T = 0; T < NKT; ++T) {
      const unsigned short* SP = sm + sl * SLOT;
      if (T < NKT - 2) ST_B(s2, (T + 2) * 64);

#pragma unroll
      for (int ks = 0; ks < 2; ++ks) {
        const int kb = T * 64 + ks * 32 + l4 * 8;
        const int cb = ks ? cb1 : cb0;
        // Issue A loads (per-lane, fp32) first so latency hides under ds_reads.
        float4 a0 = *(const float4*)(pA[0] + kb);
        float4 a1 = *(const float4*)(pA[0] + kb + 4);
        float4 b0 = *(const float4*)(pA[1] + kb);
        float4 b1 = *(const float4*)(pA[1] + kb + 4);
        float4 c0 = *(const float4*)(pA[2] + kb);
        float4 c1 = *(const float4*)(pA[2] + kb + 4);
        float4 d0 = *(const float4*)(pA[3] + kb);
        float4 d1 = *(const float4*)(pA[3] + kb + 4);
        short8 fb0 = *(const short8*)(SP + brow + 0 * 1024 + cb);
        short8 fb1 = *(const short8*)(SP + brow + 1 * 1024 + cb);
        short8 fb2 = *(const short8*)(SP + brow + 2 * 1024 + cb);
        short8 fb3 = *(const short8*)(SP + brow + 3 * 1024 + cb);
        short8 fb4 = *(const short8*)(SP + brow + 4 * 1024 + cb);
        short8 fb5 = *(const short8*)(SP + brow + 5 * 1024 + cb);
        short8 fb6 = *(const short8*)(SP + brow + 6 * 1024 + cb);
        short8 fb7 = *(const short8*)(SP + brow + 7 * 1024 + cb);
        short8 fa0 = cvt_frag(a0, a1);
        short8 fa1 = cvt_frag(b0, b1);
        short8 fa2 = cvt_frag(c0, c1);
        short8 fa3 = cvt_frag(d0, d1);
        MM(acc[0][0], fa0, fb0); MM(acc[0][1], fa0, fb1);
        MM(acc[0][2], fa0, fb2); MM(acc[0][3], fa0, fb3);
        MM(acc[0][4], fa0, fb4); MM(acc[0][5], fa0, fb5);
        MM(acc[0][6], fa0, fb6); MM(acc[0][7], fa0, fb7);
        MM(acc[1][0], fa1, fb0); MM(acc[1][1], fa1, fb1);
        MM(acc[1][2], fa1, fb2); MM(acc[1][3], fa1, fb3);
        MM(acc[1][4], fa1, fb4); MM(acc[1][5], fa1, fb5);
        MM(acc[1][6], fa1, fb6); MM(acc[1][7], fa1, fb7);
        MM(acc[2][0], fa2, fb0); MM(acc[2][1], fa2, fb1);
        MM(acc[2][2], fa2, fb2); MM(acc[2][3], fa2, fb3);
        MM(acc[2][4], fa2, fb4); MM(acc[2][5], fa2, fb5);
        MM(acc[2][6], fa2, fb6); MM(acc[2][7], fa2, fb7);
        MM(acc[3][0], fa3, fb0); MM(acc[3][1], fa3, fb1);
        MM(acc[3][2], fa3, fb2); MM(acc[3][3], fa3, fb3);
        MM(acc[3][4], fa3, fb4); MM(acc[3][5], fa3, fb5);
        MM(acc[3][6], fa3, fb6); MM(acc[3][7], fa3, fb7);
      }

      // B[T+1] must have landed before the next tile's ds_reads. A loads of
      // this tile already completed (their results were consumed above), so
      // the only outstanding VMEM is B[T+2]'s 4 loads.
      if (T < NKT - 2)       { asm volatile("s_waitcnt vmcnt(4)" ::: "memory"); }
      else if (T == NKT - 2) { asm volatile("s_waitcnt vmcnt(0)" ::: "memory"); }
      BAR();

      sl = (sl == 2) ? 0 : sl + 1;
      s2 = (s2 == 2) ? 0 : s2 + 1;
    }
#undef ST_B

    // Epilogue: bias + relu, masked rows past the expert tail.
#pragma unroll
    for (int n = 0; n < 8; ++n) {
      int col = n0 + n * 16 + l15;
      float bv = bias[e * HID + col];
#pragma unroll
      for (int m = 0; m < 4; ++m) {
#pragma unroll
        for (int q = 0; q < 4; ++q) {
          int r = aBase + w * 64 + m * 16 + l4 * 4 + q;
          if (r < hi) {
            float v = acc[m][n][q] + bv;
            out[(size_t)r * HID + col] = v > 0.f ? v : 0.f;
          }
        }
      }
    }

    // Block-uniform job steal.
    __syncthreads();
    if (t == 0) next_j = atomicAdd(qcnt, 1);
    __syncthreads();
    j = next_j;
  }
}

// ---------------------------------------------------------------------------
extern "C" void kernel_launch(void* const* d_in, const int* in_sizes, int n_in,
                              void* d_out, int out_size, void* d_ws, size_t ws_size,
                              hipStream_t stream) {
  const float* x   = (const float*)d_in[0];
  const int*   idx = (const int*)d_in[1];
  const float* W   = (const float*)d_in[2];
  const float* b   = (const float*)d_in[3];
  float* out = (float*)d_out;

  char* ws = (char*)d_ws;
  unsigned short* Wt = (unsigned short*)ws;                                   // 64 MB
  int* perm  = (int*)(ws + (size_t)N_EXP * DIM * HID * 2);
  int* offs  = perm + N_TOK;
  int* bands = offs + 16;
  int* qcnt  = bands + 4096;

  sort_experts<<<1, 256, 0, stream>>>(idx, perm, offs, bands, qcnt);
  prep_w<<<8192, 256, 0, stream>>>(W, Wt);
  grouped_gemm<<<512, 256, 0, stream>>>(x, perm, Wt, b, offs, bands, qcnt, out);
}

// Round 11
// 194.072 us; speedup vs baseline: 2.0878x; 2.0878x over previous
//
#include <hip/hip_runtime.h>

// Problem constants
#define N_TOK 8192
#define N_EXP 8
#define DIM   2048
#define HID   2048

typedef __attribute__((ext_vector_type(8))) short short8;
typedef __attribute__((ext_vector_type(4))) float f32x4;
typedef __attribute__((ext_vector_type(4))) unsigned short ushort4v;

__device__ inline unsigned short f2bf(float f) {
  unsigned int u = __builtin_bit_cast(unsigned int, f);
  unsigned int r = u + 0x7FFFu + ((u >> 16) & 1u);   // round-to-nearest-even
  return (unsigned short)(r >> 16);
}

// ---------------------------------------------------------------------------
// Kernel 1: stable counting sort by expert id + 256-row band table + per-XCD
// work-queue counters. perm[p] = source row; offs[e..e+1] = bounds;
// bands[0] = nbands, bands[1+b] = e | (mt << 8); qcnt[x] = 32 (queue start).
// ---------------------------------------------------------------------------
__global__ __launch_bounds__(256) void sort_experts(const int* __restrict__ idx,
                                                    int* __restrict__ perm,
                                                    int* __restrict__ offs,
                                                    int* __restrict__ bands,
                                                    int* __restrict__ qcnt) {
  __shared__ int cnt[256][8];
  __shared__ int base[8];
  const int t = threadIdx.x;
  int local[8] = {0,0,0,0,0,0,0,0};
  const int r0 = t * 32;
  for (int i = 0; i < 32; ++i) {
    int e = idx[r0 + i] & 7;
    ++local[e];
  }
#pragma unroll
  for (int e = 0; e < 8; ++e) cnt[t][e] = local[e];
  __syncthreads();
  if (t < 8) {
    int s = 0;
    for (int i = 0; i < 256; ++i) { int v = cnt[i][t]; cnt[i][t] = s; s += v; }
    base[t] = s;
    qcnt[t] = 32;                        // per-XCD queue starts after 32 slots
  }
  __syncthreads();
  if (t == 0) {
    int s = 0, nb = 0;
    for (int e = 0; e < 8; ++e) {
      int v = base[e];
      offs[e] = s; base[e] = s; s += v;
      int nm = (v + 255) >> 8;           // 256-row bands
      for (int mt = 0; mt < nm; ++mt) bands[1 + nb++] = e | (mt << 8);
    }
    offs[8] = s;
    bands[0] = nb;
  }
  __syncthreads();
  int pos[8];
#pragma unroll
  for (int e = 0; e < 8; ++e) pos[e] = base[e] + cnt[t][e];
  for (int i = 0; i < 32; ++i) {
    int r = r0 + i;
    int e = idx[r] & 7;
    perm[pos[e]++] = r;
  }
}

// ---------------------------------------------------------------------------
// Kernel 2: merged prep. Blocks [0,8192): gather+convert x (sorted bf16).
// Blocks [8192,16384): W[e][d][h] fp32 -> Wt[e][h][d] bf16 (LDS transpose).
// ---------------------------------------------------------------------------
__global__ __launch_bounds__(256) void prep(const float* __restrict__ x,
                                            const int* __restrict__ perm,
                                            unsigned short* __restrict__ xs,
                                            const float* __restrict__ W,
                                            unsigned short* __restrict__ Wt) {
  __shared__ unsigned short tile[64][68];
  const int t = threadIdx.x;
  if (blockIdx.x < 8192) {
    int gid = blockIdx.x * 256 + t;
    int p = gid >> 8;
    int c = gid & 255;
    int src = perm[p];
    const float* sp = x + (size_t)src * DIM + c * 8;
    float4 a = *(const float4*)sp;
    float4 b = *(const float4*)(sp + 4);
    short8 o;
    o[0] = (short)f2bf(a.x); o[1] = (short)f2bf(a.y);
    o[2] = (short)f2bf(a.z); o[3] = (short)f2bf(a.w);
    o[4] = (short)f2bf(b.x); o[5] = (short)f2bf(b.y);
    o[6] = (short)f2bf(b.z); o[7] = (short)f2bf(b.w);
    *(short8*)(xs + (size_t)p * DIM + c * 8) = o;
  } else {
    const int b = blockIdx.x - 8192;
    const int e  = b >> 10;
    const int d0 = ((b >> 5) & 31) * 64;
    const int h0 = (b & 31) * 64;
    const int cr = t & 15;
    const int rr = t >> 4;
    const float* Wp = W + ((size_t)e * DIM + d0) * HID + h0;
#pragma unroll
    for (int i = 0; i < 4; ++i) {
      int d = rr + i * 16;
      float4 v = *(const float4*)(Wp + (size_t)d * HID + cr * 4);
      ushort4v o;
      o[0] = f2bf(v.x); o[1] = f2bf(v.y); o[2] = f2bf(v.z); o[3] = f2bf(v.w);
      *(ushort4v*)&tile[d][cr * 4] = o;
    }
    __syncthreads();
    unsigned short* op = Wt + ((size_t)e * HID + h0) * DIM + d0;
#pragma unroll
    for (int i = 0; i < 4; ++i) {
      int h = rr + i * 16;
      ushort4v o;
      o[0] = tile[cr * 4 + 0][h];
      o[1] = tile[cr * 4 + 1][h];
      o[2] = tile[cr * 4 + 2][h];
      o[3] = tile[cr * 4 + 3][h];
      *(ushort4v*)(op + (size_t)h * DIM + cr * 4) = o;
    }
  }
}

// ---------------------------------------------------------------------------
// Kernel 3: PERSISTENT grouped GEMM with XCD-AFFINE job queues.
// 256 blocks x 512 thr (8 waves, 4M x 2N, per-wave 64x64). Job = 256(M) x
// 128(N); XCD x (= blockIdx&7, HW round-robin) owns N-tiles {2x, 2x+1} ->
// its two B-panels (~1MB) stay L2-resident; per-XCD job order is band-major
// PAIRS (i = 2*band + half) so the 2 jobs sharing an A-band are stolen
// nearly simultaneously (one L3 fetch, L2-hit for the twin).
// Inner loop: R6-verified (BK=64, 3 LDS slots 144 KiB, stage tile T+2,
// 2 phases/K-tile, vmcnt(6) per tile, swizzle byte[6:4]^=row[2:0]).
// ---------------------------------------------------------------------------
#define NKT 32           // K-tiles of 64
#define SLOT 24576       // ushorts: A [0,16384) = 256x64, B [16384,24576) = 128x64

#define MM(D,A,B) D = __builtin_amdgcn_mfma_f32_16x16x32_bf16(A, B, D, 0, 0, 0)
#define GLD(SRC, DST) __builtin_amdgcn_global_load_lds( \
    (const __attribute__((address_space(1))) void*)(SRC), \
    (__attribute__((address_space(3))) void*)(DST), 16, 0, 0)
#define BAR() __builtin_amdgcn_s_barrier()
#define PRIO(x) __builtin_amdgcn_s_setprio(x)

__global__ __launch_bounds__(512, 2) void grouped_gemm(
    const unsigned short* __restrict__ xs,
    const unsigned short* __restrict__ Wt,
    const float* __restrict__ bias,
    const int* __restrict__ offs,
    const int* __restrict__ bands,
    int* __restrict__ qcnt,
    float* __restrict__ out) {
  __shared__ __align__(16) unsigned short sm[3 * SLOT];   // 144 KiB
  __shared__ int next_i;

  const int t    = threadIdx.x;
  const int lane = t & 63;
  const int wid  = t >> 6;
  const int wr   = wid >> 1;   // 0..3  (M quarter: rows wr*64)
  const int wc   = wid & 1;    // 0..1  (N half:    cols wc*64)
  const int l15  = lane & 15;
  const int l4   = lane >> 4;
  const int xcd  = blockIdx.x & 7;

  // Fragment LDS offsets (ushort units); row stride 64 ush (128B).
  const int cb0  = (l4 * 8) ^ ((l15 & 7) << 3);
  const int cb1  = cb0 ^ 32;
  const int arow = (wr * 64 + l15) * 64;           // + m*1024
  const int brow = 16384 + (wc * 64 + l15) * 64;   // + n*1024

  // Staging geometry: chunk = 8KB (64 rows x 64 k-elems), thread t covers
  // row r0 = t>>3, 16B col (t&7); inverse swizzle pre-applied to k index.
  const int r0  = t >> 3;
  const int keu = ((t & 7) * 8) ^ ((r0 & 7) << 3);
  const int dA = t * 8;

  const int nj = bands[0] * 2;     // jobs owned by each XCD

  int i = blockIdx.x >> 3;         // initial slot 0..31 within this XCD
  while (i < nj) {
    const int bd  = bands[1 + (i >> 1)];
    const int e   = bd & 255;
    const int mt  = bd >> 8;
    const int nx  = (xcd << 1) | (i & 1);
    const int off = offs[e];
    const int cnt = offs[e + 1] - off;
    const int aBase = off + mt * 256;
    const int n0  = nx * 128;

    // Per-job staging source bases (element offsets at k=0).
    unsigned int pa0, pa1, pa2, pa3, pb0, pb1;
    {
      int p;
      p = aBase + 0 * 64 + r0; if (p > N_TOK - 1) p = N_TOK - 1; pa0 = (unsigned)p * 2048 + keu;
      p = aBase + 1 * 64 + r0; if (p > N_TOK - 1) p = N_TOK - 1; pa1 = (unsigned)p * 2048 + keu;
      p = aBase + 2 * 64 + r0; if (p > N_TOK - 1) p = N_TOK - 1; pa2 = (unsigned)p * 2048 + keu;
      p = aBase + 3 * 64 + r0; if (p > N_TOK - 1) p = N_TOK - 1; pa3 = (unsigned)p * 2048 + keu;
      unsigned int eW = (unsigned)e * (DIM * HID);
      pb0 = eW + (unsigned)(n0 + 0 * 64 + r0) * 2048 + keu;
      pb1 = eW + (unsigned)(n0 + 1 * 64 + r0) * 2048 + keu;
    }

#define ST_HALF1(SBASE, KOFS) do { \
    GLD(xs + pa0 + (KOFS), sm + (SBASE) + 0 * 4096 + dA); \
    GLD(xs + pa1 + (KOFS), sm + (SBASE) + 1 * 4096 + dA); \
    GLD(xs + pa2 + (KOFS), sm + (SBASE) + 2 * 4096 + dA); } while (0)
#define ST_HALF2(SBASE, KOFS) do { \
    GLD(xs + pa3 + (KOFS), sm + (SBASE) + 3 * 4096 + dA); \
    GLD(Wt + pb0 + (KOFS), sm + (SBASE) + 16384 + 0 * 4096 + dA); \
    GLD(Wt + pb1 + (KOFS), sm + (SBASE) + 16384 + 1 * 4096 + dA); } while (0)

    f32x4 acc[4][4] = {};

    // Prologue: tiles 0,1 -> slots 0,1.
    ST_HALF1(0, 0);        ST_HALF2(0, 0);
    ST_HALF1(SLOT, 64);    ST_HALF2(SLOT, 64);
    asm volatile("s_waitcnt vmcnt(6)" ::: "memory");   // tile0 landed
    BAR();

    short8 fa0, fa1, fa2, fa3, fb0, fb1, fb2, fb3;
    int sl = 0;   // slot of tile T
    int s2 = 2;   // slot of tile T+2

#pragma unroll 1
    for (int T = 0; T < NKT; ++T) {
      const unsigned short* SP = sm + sl * SLOT;
      const int sb = s2 * SLOT;
      const int kofs = (T + 2) * 64;
      const bool st = (T < NKT - 2);

      // ---- phase 0: ksub0 ----
      fa0 = *(const short8*)(SP + arow + 0 * 1024 + cb0);
      fa1 = *(const short8*)(SP + arow + 1 * 1024 + cb0);
      fa2 = *(const short8*)(SP + arow + 2 * 1024 + cb0);
      fa3 = *(const short8*)(SP + arow + 3 * 1024 + cb0);
      fb0 = *(const short8*)(SP + brow + 0 * 1024 + cb0);
      fb1 = *(const short8*)(SP + brow + 1 * 1024 + cb0);
      fb2 = *(const short8*)(SP + brow + 2 * 1024 + cb0);
      fb3 = *(const short8*)(SP + brow + 3 * 1024 + cb0);
      if (st) ST_HALF1(sb, kofs);
      BAR(); PRIO(1);
      MM(acc[0][0],fa0,fb0); MM(acc[0][1],fa0,fb1); MM(acc[0][2],fa0,fb2); MM(acc[0][3],fa0,fb3);
      MM(acc[1][0],fa1,fb0); MM(acc[1][1],fa1,fb1); MM(acc[1][2],fa1,fb2); MM(acc[1][3],fa1,fb3);
      MM(acc[2][0],fa2,fb0); MM(acc[2][1],fa2,fb1); MM(acc[2][2],fa2,fb2); MM(acc[2][3],fa2,fb3);
      MM(acc[3][0],fa3,fb0); MM(acc[3][1],fa3,fb1); MM(acc[3][2],fa3,fb2); MM(acc[3][3],fa3,fb3);
      PRIO(0); BAR();

      // ---- phase 1: ksub1 ----
      fa0 = *(const short8*)(SP + arow + 0 * 1024 + cb1);
      fa1 = *(const short8*)(SP + arow + 1 * 1024 + cb1);
      fa2 = *(const short8*)(SP + arow + 2 * 1024 + cb1);
      fa3 = *(const short8*)(SP + arow + 3 * 1024 + cb1);
      fb0 = *(const short8*)(SP + brow + 0 * 1024 + cb1);
      fb1 = *(const short8*)(SP + brow + 1 * 1024 + cb1);
      fb2 = *(const short8*)(SP + brow + 2 * 1024 + cb1);
      fb3 = *(const short8*)(SP + brow + 3 * 1024 + cb1);
      if (st) ST_HALF2(sb, kofs);
      BAR(); PRIO(1);
      MM(acc[0][0],fa0,fb0); MM(acc[0][1],fa0,fb1); MM(acc[0][2],fa0,fb2); MM(acc[0][3],fa0,fb3);
      MM(acc[1][0],fa1,fb0); MM(acc[1][1],fa1,fb1); MM(acc[1][2],fa1,fb2); MM(acc[1][3],fa1,fb3);
      MM(acc[2][0],fa2,fb0); MM(acc[2][1],fa2,fb1); MM(acc[2][2],fa2,fb2); MM(acc[2][3],fa2,fb3);
      MM(acc[3][0],fa3,fb0); MM(acc[3][1],fa3,fb1); MM(acc[3][2],fa3,fb2); MM(acc[3][3],fa3,fb3);
      PRIO(0);
      if (T < NKT - 2)       { asm volatile("s_waitcnt vmcnt(6)" ::: "memory"); }
      else if (T == NKT - 2) { asm volatile("s_waitcnt vmcnt(0)" ::: "memory"); }
      BAR();

      sl = (sl == 2) ? 0 : sl + 1;
      s2 = (s2 == 2) ? 0 : s2 + 1;
    }

    // Epilogue: bias + relu, masked tail rows.
#pragma unroll
    for (int n = 0; n < 4; ++n) {
      int col = n0 + wc * 64 + n * 16 + l15;
      float bv = bias[e * HID + col];
#pragma unroll
      for (int m = 0; m < 4; ++m) {
#pragma unroll
        for (int q = 0; q < 4; ++q) {
          int r = wr * 64 + m * 16 + l4 * 4 + q;
          if (mt * 256 + r < cnt) {
            float v = acc[m][n][q] + bv;
            out[(size_t)(off + mt * 256 + r) * HID + col] = v > 0.f ? v : 0.f;
          }
        }
      }
    }

    // Block-uniform steal from this XCD's queue.
    __syncthreads();
    if (t == 0) next_i = atomicAdd(&qcnt[xcd], 1);
    __syncthreads();
    i = next_i;
  }
#undef ST_HALF1
#undef ST_HALF2
}

// ---------------------------------------------------------------------------
extern "C" void kernel_launch(void* const* d_in, const int* in_sizes, int n_in,
                              void* d_out, int out_size, void* d_ws, size_t ws_size,
                              hipStream_t stream) {
  const float* x   = (const float*)d_in[0];
  const int*   idx = (const int*)d_in[1];
  const float* W   = (const float*)d_in[2];
  const float* b   = (const float*)d_in[3];
  float* out = (float*)d_out;

  char* ws = (char*)d_ws;
  unsigned short* xs = (unsigned short*)ws;                                   // 32 MB
  unsigned short* Wt = (unsigned short*)(ws + (size_t)N_TOK * DIM * 2);       // 64 MB
  int* perm  = (int*)(ws + (size_t)N_TOK * DIM * 2 + (size_t)N_EXP * DIM * HID * 2);
  int* offs  = perm + N_TOK;
  int* bands = offs + 16;
  int* qcnt  = bands + 4096;

  sort_experts<<<1, 256, 0, stream>>>(idx, perm, offs, bands, qcnt);
  prep<<<16384, 256, 0, stream>>>(x, perm, xs, W, Wt);
  grouped_gemm<<<256, 512, 0, stream>>>(xs, Wt, b, offs, bands, qcnt, out);
}